// Round 1
// baseline (139.646 us; speedup 1.0000x reference)
//
#include <hip/hip_runtime.h>
#include <cmath>
#include <cstdint>

#define INFIN __builtin_inff()

// ---------------- init scalars ----------------
__global__ void k_init(int* wsi) {
    wsi[0] = 0x7FFFFFFF;          // lvl_min accumulator
    wsi[1] = (int)0x80000000;     // lvl_max accumulator
}

// ---------------- zero-fill output ----------------
__global__ __launch_bounds__(256) void k_zero(int4* out, int n4) {
    int i = blockIdx.x * blockDim.x + threadIdx.x;
    int stride = gridDim.x * blockDim.x;
    for (; i < n4; i += stride) out[i] = make_int4(0, 0, 0, 0);
}

// ---------------- level min/max over points ----------------
__global__ __launch_bounds__(256) void k_lvl(const float* __restrict__ pts, int* wsi, int N) {
    int t = blockIdx.x * blockDim.x + threadIdx.x;
    int stride = gridDim.x * blockDim.x;
    int lmin = 0x7FFFFFFF, lmax = (int)0x80000000;
    for (int i = t; i < N; i += stride) {
        unsigned u = __float_as_uint(pts[3 * i + 2]);
        int e = (int)((u >> 23) & 0xFF) - 127;   // exact log2 for power-of-2 strides
        lmin = min(lmin, e);
        lmax = max(lmax, e);
    }
    __shared__ int smin[256], smax[256];
    smin[threadIdx.x] = lmin; smax[threadIdx.x] = lmax;
    __syncthreads();
    for (int off = 128; off > 0; off >>= 1) {
        if (threadIdx.x < off) {
            smin[threadIdx.x] = min(smin[threadIdx.x], smin[threadIdx.x + off]);
            smax[threadIdx.x] = max(smax[threadIdx.x], smax[threadIdx.x + off]);
        }
        __syncthreads();
    }
    if (threadIdx.x == 0) {
        atomicMin(&wsi[0], smin[0]);
        atomicMax(&wsi[1], smax[0]);
    }
}

// ---------------- per-gt preprocessing ----------------
__global__ void k_prep(const float* __restrict__ gtb, const int* __restrict__ wsi,
                       float* gpar, int* glvl, int K) {
    int k = blockIdx.x * blockDim.x + threadIdx.x;
    if (k >= K) return;
    float x0 = gtb[8*k+0], y0 = gtb[8*k+1], x1 = gtb[8*k+2], y1 = gtb[8*k+3];
    float x2 = gtb[8*k+4], y2 = gtb[8*k+5], x3 = gtb[8*k+6], y3 = gtb[8*k+7];
    float xmin = fminf(fminf(x0, x1), fminf(x2, x3));
    float xmax = fmaxf(fmaxf(x0, x1), fmaxf(x2, x3));
    float ymin = fminf(fminf(y0, y1), fminf(y2, y3));
    float ymax = fmaxf(fmaxf(y0, y1), fmaxf(y2, y3));
    float cx = __fmul_rn(__fadd_rn(xmin, xmax), 0.5f);   // /2 exact
    float cy = __fmul_rn(__fadd_rn(ymin, ymax), 0.5f);
    float w  = fmaxf(__fsub_rn(xmax, xmin), 1e-6f);
    float h  = fmaxf(__fsub_rn(ymax, ymin), 1e-6f);
    // (log2(w/4)+log2(h/4))/2, truncated toward zero, clipped to [lvl_min,lvl_max]
    float gf = __fmul_rn(__fadd_rn(log2f(__fmul_rn(w, 0.25f)),
                                   log2f(__fmul_rn(h, 0.25f))), 0.5f);
    int gl = (int)gf;
    gl = min(max(gl, wsi[0]), wsi[1]);
    gpar[k]       = cx;
    gpar[256 + k] = cy;
    gpar[512 + k] = w;
    gpar[768 + k] = h;
    glvl[k]       = gl;
}

// ---------------- stage 1: per-(block,gt) partial argmin over point chunk ----------------
__global__ __launch_bounds__(256) void k_stage1(const float* __restrict__ pts,
                                                const float* __restrict__ gpar,
                                                const int* __restrict__ glvl,
                                                float* __restrict__ pmin,
                                                int* __restrict__ pidx,
                                                int N, int K, int chunk) {
    __shared__ float4 sp[256];
    int b = blockIdx.x, t = threadIdx.x;
    int start = b * chunk;
    int end = min(start + chunk, N);
    float cx = 0.f, cy = 0.f, w = 1.f, h = 1.f;
    int gl = -1000;
    if (t < K) { cx = gpar[t]; cy = gpar[256 + t]; w = gpar[512 + t]; h = gpar[768 + t]; gl = glvl[t]; }
    float best = INFIN;
    int bidx = 0x7FFFFFFF;
    for (int base = start; base < end; base += 256) {
        int p = base + t;
        if (p < end) {
            float x = pts[3 * p], y = pts[3 * p + 1];
            unsigned u = __float_as_uint(pts[3 * p + 2]);
            int e = (int)((u >> 23) & 0xFF) - 127;
            sp[t] = make_float4(x, y, __int_as_float(e), 0.f);
        }
        __syncthreads();
        int m = min(256, end - base);
        #pragma unroll 4
        for (int i = 0; i < m; ++i) {
            float4 q = sp[i];                      // broadcast read, conflict-free
            int pl = __float_as_int(q.z);
            float dx = __fdiv_rn(__fsub_rn(q.x, cx), w);
            float dy = __fdiv_rn(__fsub_rn(q.y, cy), h);
            float d  = __fsqrt_rn(__fadd_rn(__fmul_rn(dx, dx), __fmul_rn(dy, dy)));
            if ((pl == gl) && (d < best)) { best = d; bidx = base + i; }  // strict < => first idx on ties
        }
        __syncthreads();
    }
    if (t < K) {
        pmin[b * 256 + t] = best;
        pidx[b * 256 + t] = bidx;
    }
}

// ---------------- stage 2: reduce partials per gt ----------------
__global__ __launch_bounds__(256) void k_stage2(const float* __restrict__ pminb,
                                                const int* __restrict__ pidxb,
                                                float* mind, int* nearg, int B) {
    int k = blockIdx.x, t = threadIdx.x;
    float best = INFIN;
    int bidx = 0x7FFFFFFF;
    for (int b = t; b < B; b += 256) {
        float d = pminb[b * 256 + k];
        int ix  = pidxb[b * 256 + k];
        if (d < best || (d == best && ix < bidx)) { best = d; bidx = ix; }
    }
    __shared__ float sd[256];
    __shared__ int si[256];
    sd[t] = best; si[t] = bidx;
    __syncthreads();
    for (int off = 128; off > 0; off >>= 1) {
        if (t < off) {
            float d2 = sd[t + off]; int i2 = si[t + off];
            if (d2 < sd[t] || (d2 == sd[t] && i2 < si[t])) { sd[t] = d2; si[t] = i2; }
        }
        __syncthreads();
    }
    if (t == 0) { mind[k] = sd[0]; nearg[k] = si[0]; }
}

// ---------------- finalize: contention resolve + scatter ----------------
__global__ __launch_bounds__(256) void k_final(const float* __restrict__ mind,
                                               const int* __restrict__ nearg,
                                               const int* __restrict__ glab,
                                               int* out_inds, int* out_labels, int K) {
    __shared__ float sd[256];
    __shared__ int sn[256];
    __shared__ int swin[256];
    int k = threadIdx.x;
    float dk = INFIN; int nk = -1;
    if (k < K) { dk = mind[k]; nk = nearg[k]; }
    sd[k] = dk; sn[k] = nk;
    __syncthreads();
    bool valid = (dk < INFIN);
    float bestv = INFIN;
    for (int j = 0; j < K; ++j) {
        if (sn[j] == nk) {
            float dj = sd[j];          // invalid gts carry INF already
            if (dj < bestv) bestv = dj;
        }
    }
    bool win = valid && (dk == bestv);
    swin[k] = win ? 1 : 0;
    __syncthreads();
    bool owner = win;
    if (win) {
        for (int j = 0; j < k; ++j) {
            if (sn[j] == nk && swin[j]) { owner = false; break; }
        }
    }
    if (owner) {
        out_inds[nk]   = k + 1;
        out_labels[nk] = glab[k];
    }
}

extern "C" void kernel_launch(void* const* d_in, const int* in_sizes, int n_in,
                              void* d_out, int out_size, void* d_ws, size_t ws_size,
                              hipStream_t stream) {
    const float* pts = (const float*)d_in[0];
    const float* gtb = (const float*)d_in[1];
    const int* glab  = (const int*)d_in[2];
    int N = in_sizes[0] / 3;
    int K = in_sizes[1] / 8;     // K <= 256 assumed (K == 256 here)
    int* out_inds   = (int*)d_out;
    int* out_labels = out_inds + N;

    char* wsc = (char*)d_ws;
    int*   wsi   = (int*)wsc;                 // [0]=lvl_min [1]=lvl_max
    float* gpar  = (float*)(wsc + 64);        // cx[256],cy[256],w[256],h[256]
    int*   glvl  = (int*)(wsc + 64 + 4096);
    float* mind  = (float*)(wsc + 64 + 5120);
    int*   nearg = (int*)(wsc + 64 + 6144);
    // partial buffers start at 16 KiB
    int B = 1024;
    while (B > 64 && (size_t)16384 + (size_t)B * 2048 > ws_size) B >>= 1;
    float* pminb = (float*)(wsc + 16384);
    int*   pidxb = (int*)(wsc + 16384 + (size_t)B * 1024);

    int n4 = (out_size * 4) / 16;   // out is int32; fill with int4 stores
    k_zero<<<256, 256, 0, stream>>>((int4*)d_out, n4);
    k_init<<<1, 1, 0, stream>>>(wsi);
    k_lvl<<<256, 256, 0, stream>>>(pts, wsi, N);
    k_prep<<<(K + 255) / 256, 256, 0, stream>>>(gtb, wsi, gpar, glvl, K);
    int chunk = (N + B - 1) / B;
    k_stage1<<<B, 256, 0, stream>>>(pts, gpar, glvl, pminb, pidxb, N, K, chunk);
    k_stage2<<<K, 256, 0, stream>>>(pminb, pidxb, mind, nearg, B);
    k_final<<<1, 256, 0, stream>>>(mind, nearg, glab, out_inds, out_labels, K);
}